// Round 6
// baseline (434.766 us; speedup 1.0000x reference)
//
#include <hip/hip_runtime.h>

#define HID 64
#define IN_C 16
#define R 4

__device__ __forceinline__ float lanebcf(float v, int l) {
    return __int_as_float(__builtin_amdgcn_readlane(__float_as_int(v), l));
}

// blocks [0,nb0): h = relu(x@W0+b0)   blocks [nb0,nb0+nbh): cnt[dst]++
__global__ void k_node0_hist(const float* __restrict__ x, const float* __restrict__ W0,
                             const float* __restrict__ b0, float* __restrict__ h, int N,
                             const int* __restrict__ ei, int* __restrict__ cnt, int E,
                             int nb0) {
    if ((int)blockIdx.x < nb0) {
        int gid = blockIdx.x * 256 + threadIdx.x;
        if (gid >= N * HID) return;
        int n = gid >> 6;
        int c = gid & 63;
        const float* xr = x + (size_t)n * IN_C;
        float acc = b0[c];
#pragma unroll
        for (int k = 0; k < IN_C; ++k) acc = fmaf(xr[k], W0[k * HID + c], acc);
        h[gid] = fmaxf(acc, 0.f);
    } else {
        int e = (blockIdx.x - nb0) * 256 + threadIdx.x;
        if (e < E) atomicAdd(&cnt[ei[E + e]], 1);
    }
}

// Combined weights: WZ = Mt@W1, WQ = Mb@W1  [64x64 each], cb = bM0@W1 [64]
__global__ void k_wcomb(const float* __restrict__ M0, const float* __restrict__ W1,
                        const float* __restrict__ bM0,
                        float* __restrict__ WZ, float* __restrict__ WQ,
                        float* __restrict__ cb) {
    int t = threadIdx.x;
    for (int idx = t; idx < 2 * HID * HID; idx += 256) {
        int m  = idx >> 12;          // 0 -> WZ (Mt rows), 1 -> WQ (Mb rows)
        int c  = (idx >> 6) & 63;
        int cp = idx & 63;
        const float* mrow = M0 + (size_t)(m * HID + c) * HID;
        float acc = 0.f;
#pragma unroll
        for (int k = 0; k < HID; ++k) acc = fmaf(mrow[k], W1[k * HID + cp], acc);
        (m ? WQ : WZ)[c * HID + cp] = acc;
    }
    if (t < HID) {
        float acc = 0.f;
#pragma unroll
        for (int c = 0; c < HID; ++c) acc = fmaf(bM0[c], W1[c * HID + t], acc);
        cb[t] = acc;
    }
}

// Per node: z = h@WZ (overwrites h); p = h@W1 + b1; q = h@WQ + cb
__global__ __launch_bounds__(256) void k_pre(
    float* __restrict__ hz, float* __restrict__ p, float* __restrict__ q,
    const float* __restrict__ WZm, const float* __restrict__ WQm,
    const float* __restrict__ cb, const float* __restrict__ W1,
    const float* __restrict__ b1, int N)
{
    __shared__ float lWZ[HID * HID];
    __shared__ float lWQ[HID * HID];
    __shared__ float lW1[HID * HID];
    for (int i = threadIdx.x; i < HID * HID; i += 256) {
        lWZ[i] = WZm[i]; lWQ[i] = WQm[i]; lW1[i] = W1[i];
    }
    __syncthreads();

    int lane = threadIdx.x & 63;
    int wid = (blockIdx.x * blockDim.x + threadIdx.x) >> 6;
    int nw = (gridDim.x * blockDim.x) >> 6;
    float cbl = cb[lane];
    float b1l = b1[lane];

    for (int n0 = wid * R; n0 < N; n0 += nw * R) {
        float hv[R], zz[R], pp[R], qq[R];
#pragma unroll
        for (int r = 0; r < R; ++r) {
            hv[r] = (n0 + r < N) ? hz[(size_t)(n0 + r) * HID + lane] : 0.f;
            zz[r] = 0.f; pp[r] = b1l; qq[r] = cbl;
        }
#pragma unroll
        for (int k = 0; k < HID; ++k) {
            float wz = lWZ[k * HID + lane];
            float wp = lW1[k * HID + lane];
            float wq = lWQ[k * HID + lane];
#pragma unroll
            for (int r = 0; r < R; ++r) {
                float hk = lanebcf(hv[r], k);
                zz[r] = fmaf(hk, wz, zz[r]);
                pp[r] = fmaf(hk, wp, pp[r]);
                qq[r] = fmaf(hk, wq, qq[r]);
            }
        }
#pragma unroll
        for (int r = 0; r < R; ++r) {
            if (n0 + r < N) {
                size_t o = (size_t)(n0 + r) * HID + lane;
                hz[o] = zz[r]; p[o] = pp[r]; q[o] = qq[r];
            }
        }
    }
}

// Per-block (1024 elems) exclusive scan of cnt -> rs; block sums -> bsum
__global__ void k_scan1(const int* __restrict__ cnt, int* __restrict__ rs,
                        int* __restrict__ bsum, int N) {
    __shared__ int lds[256];
    int t = threadIdx.x;
    int base = blockIdx.x * 1024 + t * 4;
    int v0 = 0, v1 = 0, v2 = 0, v3 = 0;
    if (base + 3 < N) {
        int4 v = *reinterpret_cast<const int4*>(cnt + base);
        v0 = v.x; v1 = v.y; v2 = v.z; v3 = v.w;
    } else {
        if (base + 0 < N) v0 = cnt[base + 0];
        if (base + 1 < N) v1 = cnt[base + 1];
        if (base + 2 < N) v2 = cnt[base + 2];
        if (base + 3 < N) v3 = cnt[base + 3];
    }
    int s = v0 + v1 + v2 + v3;
    lds[t] = s;
    __syncthreads();
#pragma unroll
    for (int off = 1; off < 256; off <<= 1) {
        int x = (t >= off) ? lds[t - off] : 0;
        __syncthreads();
        lds[t] += x;
        __syncthreads();
    }
    int excl = lds[t] - s;
    if (t == 255) bsum[blockIdx.x] = lds[255];
    if (base + 0 < N) rs[base + 0] = excl;
    if (base + 1 < N) rs[base + 1] = excl + v0;
    if (base + 2 < N) rs[base + 2] = excl + v0 + v1;
    if (base + 3 < N) rs[base + 3] = excl + v0 + v1 + v2;
}

// rs[i] += exclusive_scan(bsum)[i>>10]; cursor=rs; rs[N]=E
__global__ void k_scan_add(int* __restrict__ rs, int* __restrict__ cursor,
                           const int* __restrict__ bsum, int NB, int N, int E) {
    __shared__ int lds[256];
    int t = threadIdx.x;
    int v = (t < NB) ? bsum[t] : 0;
    lds[t] = v;
    __syncthreads();
#pragma unroll
    for (int off = 1; off < 256; off <<= 1) {
        int x = (t >= off) ? lds[t - off] : 0;
        __syncthreads();
        lds[t] += x;
        __syncthreads();
    }
    __shared__ int excl[256];
    excl[t] = lds[t] - v;
    __syncthreads();
    int i = blockIdx.x * blockDim.x + t;
    if (i < N) {
        int val = rs[i] + excl[i >> 10];
        rs[i] = val;
        cursor[i] = val;
    }
    if (i == 0) rs[N] = E;
}

__global__ void k_scatter(const int* __restrict__ ei, int* __restrict__ cursor,
                          int* __restrict__ csr, int E) {
    int e = blockIdx.x * blockDim.x + threadIdx.x;
    if (e >= E) return;
    int srcn = ei[e];
    int dstn = ei[E + e];
    int pos = atomicAdd(&cursor[dstn], 1);
    csr[pos] = srcn;
}

// Pure gather + elementwise epilogue. No LDS, no matvecs.
// Wave = 4 groups x 16 lanes; group g -> node n0+g; lane ql holds channels 4ql..4ql+3.
__global__ __launch_bounds__(256) void k_final(
    const float* __restrict__ z, const float* __restrict__ p, const float* __restrict__ q,
    const int* __restrict__ rs, const int* __restrict__ csr,
    const float* __restrict__ W2, const float* __restrict__ b2,
    float* __restrict__ out, int N)
{
    int lane = threadIdx.x & 63;
    int g    = lane >> 4;
    int ql   = lane & 15;
    int wid  = (blockIdx.x * blockDim.x + threadIdx.x) >> 6;
    int nw   = (gridDim.x * blockDim.x) >> 6;

    float4 w2v = *reinterpret_cast<const float4*>(W2 + 4 * ql);
    float b2s = b2[0];
    const float* zq = z + ql * 4;

    for (int n0 = wid * R; n0 < N; n0 += nw * R) {
        int ng   = n0 + g;
        bool okg = ng < N;
        int beg  = okg ? rs[ng] : 0;
        int end  = okg ? rs[ng + 1] : 0;
        int deg  = end - beg;

        // independent streams: p/q chunks for this node (issue before gather)
        float4 p4 = okg ? *reinterpret_cast<const float4*>(p + (size_t)ng * HID + 4 * ql)
                        : make_float4(0.f, 0.f, 0.f, 0.f);
        float4 q4 = okg ? *reinterpret_cast<const float4*>(q + (size_t)ng * HID + 4 * ql)
                        : make_float4(0.f, 0.f, 0.f, 0.f);

        int md = deg;
        md = max(md, __shfl_xor(md, 16));
        md = max(md, __shfl_xor(md, 32));

        float4 acc = {0.f, 0.f, 0.f, 0.f};
        for (int c = 0; c < md; c += 16) {
            int rem = deg - c;
            int idxv = (ql < rem) ? csr[beg + c + ql] : -1;
#pragma unroll
            for (int jb = 0; jb < 2; ++jb) {
                if (jb == 1 && md <= c + 8) break;
                int id[8];
#pragma unroll
                for (int u = 0; u < 8; ++u)
                    id[u] = __shfl(idxv, g * 16 + jb * 8 + u);
                float4 v[8];
#pragma unroll
                for (int u = 0; u < 8; ++u) {
                    int safe = (id[u] < 0) ? 0 : id[u];
                    v[u] = *reinterpret_cast<const float4*>(zq + (size_t)safe * HID);
                }
#pragma unroll
                for (int u = 0; u < 8; ++u) {
                    if (id[u] >= 0) {
                        acc.x += v[u].x; acc.y += v[u].y;
                        acc.z += v[u].z; acc.w += v[u].w;
                    }
                }
            }
        }

        float rcpd = 1.f / fmaxf((float)deg, 1.f);
        float flag = (deg > 0) ? 1.f : 0.f;
        float4 y;
        y.x = p4.x + flag * (acc.x * rcpd + q4.x);
        y.y = p4.y + flag * (acc.y * rcpd + q4.y);
        y.z = p4.z + flag * (acc.z * rcpd + q4.z);
        y.w = p4.w + flag * (acc.w * rcpd + q4.w);

        float part = fmaxf(y.x, 0.f) * w2v.x + fmaxf(y.y, 0.f) * w2v.y +
                     fmaxf(y.z, 0.f) * w2v.z + fmaxf(y.w, 0.f) * w2v.w;
#pragma unroll
        for (int off = 1; off < 16; off <<= 1) part += __shfl_xor(part, off);
        if (ql == 0 && okg) out[ng] = part + b2s;
    }
}

extern "C" void kernel_launch(void* const* d_in, const int* in_sizes, int n_in,
                              void* d_out, int out_size, void* d_ws, size_t ws_size,
                              hipStream_t stream) {
    const float* x   = (const float*)d_in[0];
    const int*   ei  = (const int*)d_in[1];
    const float* W0  = (const float*)d_in[2];
    const float* b0  = (const float*)d_in[3];
    const float* W1  = (const float*)d_in[4];
    const float* b1  = (const float*)d_in[5];
    const float* W2  = (const float*)d_in[6];
    const float* b2  = (const float*)d_in[7];
    const float* M0  = (const float*)d_in[8];
    const float* bM0 = (const float*)d_in[9];

    int N = in_sizes[0] / IN_C;
    int E = in_sizes[1] / 2;
    int NB = (N + 1023) / 1024;   // <= 256 assumed

    float* hz     = (float*)d_ws;                    // N*64: h, overwritten by z
    float* p      = hz + (size_t)N * HID;            // N*64
    float* q      = p + (size_t)N * HID;             // N*64
    int*   rs     = (int*)(q + (size_t)N * HID);     // N+1
    int*   cursor = rs + (N + 1);                    // N (doubles as cnt)
    int*   bsum   = cursor + N;                      // 256
    float* WZ     = (float*)(bsum + 256);            // 4096
    float* WQ     = WZ + HID * HID;                  // 4096
    float* cb     = WQ + HID * HID;                  // 64
    int*   csr    = (int*)(cb + HID);                // E
    float* out    = (float*)d_out;

    int nb0 = (N * HID + 255) / 256;
    int nbh = (E + 255) / 256;

    hipMemsetAsync(cursor, 0, (size_t)N * sizeof(int), stream);
    k_wcomb<<<1, 256, 0, stream>>>(M0, W1, bM0, WZ, WQ, cb);
    k_node0_hist<<<nb0 + nbh, 256, 0, stream>>>(x, W0, b0, hz, N, ei, cursor, E, nb0);
    k_pre<<<512, 256, 0, stream>>>(hz, p, q, WZ, WQ, cb, W1, b1, N);
    k_scan1<<<NB, 256, 0, stream>>>(cursor, rs, bsum, N);
    k_scan_add<<<(N + 255) / 256, 256, 0, stream>>>(rs, cursor, bsum, NB, N, E);
    k_scatter<<<(E + 255) / 256, 256, 0, stream>>>(ei, cursor, csr, E);
    k_final<<<1536, 256, 0, stream>>>(hz, p, q, rs, csr, W2, b2, out, N);
}

// Round 7
// 297.775 us; speedup vs baseline: 1.4600x; 1.4600x over previous
//
#include <hip/hip_runtime.h>

#define HID 64
#define IN_C 16
#define R 4

__device__ __forceinline__ float lanebcf(float v, int l) {
    return __int_as_float(__builtin_amdgcn_readlane(__float_as_int(v), l));
}

// --- combined weights: WZ = Mt@W1, WQ = Mb@W1 (64x64), cb = bM0@W1 (64) ---
__global__ void k_wcomb(const float* __restrict__ M0, const float* __restrict__ W1,
                        const float* __restrict__ bM0,
                        float* __restrict__ WZ, float* __restrict__ WQ,
                        float* __restrict__ cb) {
    int idx = blockIdx.x * 256 + threadIdx.x;     // 32 blocks cover 8192 outputs
    if (idx < 2 * HID * HID) {
        int m  = idx >> 12;
        int c  = (idx >> 6) & 63;
        int cp = idx & 63;
        const float* mrow = M0 + (size_t)(m * HID + c) * HID;
        float acc = 0.f;
#pragma unroll
        for (int k = 0; k < HID; ++k) acc = fmaf(mrow[k], W1[k * HID + cp], acc);
        (m ? WQ : WZ)[c * HID + cp] = acc;
    }
    if (blockIdx.x == 0 && threadIdx.x < HID) {
        int t = threadIdx.x;
        float acc = 0.f;
#pragma unroll
        for (int c = 0; c < HID; ++c) acc = fmaf(bM0[c], W1[c * HID + t], acc);
        cb[t] = acc;
    }
}

// --- fused: h = relu(x@W0+b0) in-register, then z=h@WZ, p=h@W1+b1, q=h@WQ+cb ---
__global__ __launch_bounds__(256) void k_node0pre(
    const float* __restrict__ x, const float* __restrict__ W0, const float* __restrict__ b0,
    const float* __restrict__ WZm, const float* __restrict__ WQm, const float* __restrict__ cbv,
    const float* __restrict__ W1, const float* __restrict__ b1,
    float* __restrict__ z, float* __restrict__ p, float* __restrict__ q, int N)
{
    __shared__ float lWZ[HID * HID];
    __shared__ float lWQ[HID * HID];
    __shared__ float lW1[HID * HID];
    __shared__ float lW0[IN_C * HID];
    for (int i = threadIdx.x; i < HID * HID; i += 256) {
        lWZ[i] = WZm[i]; lWQ[i] = WQm[i]; lW1[i] = W1[i];
    }
    for (int i = threadIdx.x; i < IN_C * HID; i += 256) lW0[i] = W0[i];
    __syncthreads();

    int lane = threadIdx.x & 63;
    int wid = (blockIdx.x * 256 + threadIdx.x) >> 6;
    int nw  = (gridDim.x * 256) >> 6;
    float b0l = b0[lane], b1l = b1[lane], cbl = cbv[lane];

    for (int n0 = wid * R; n0 < N; n0 += nw * R) {
        float hv[R];
#pragma unroll
        for (int r = 0; r < R; ++r) {
            int n = n0 + r;
            float acc = b0l;
            if (n < N) {
                const float* xr = x + (size_t)n * IN_C;
#pragma unroll
                for (int k = 0; k < IN_C; ++k) acc = fmaf(xr[k], lW0[k * HID + lane], acc);
            }
            hv[r] = fmaxf(acc, 0.f);
        }
        float zz[R], pp[R], qq[R];
#pragma unroll
        for (int r = 0; r < R; ++r) { zz[r] = 0.f; pp[r] = b1l; qq[r] = cbl; }
#pragma unroll
        for (int k = 0; k < HID; ++k) {
            float wz = lWZ[k * HID + lane];
            float wp = lW1[k * HID + lane];
            float wq = lWQ[k * HID + lane];
#pragma unroll
            for (int r = 0; r < R; ++r) {
                float hk = lanebcf(hv[r], k);
                zz[r] = fmaf(hk, wz, zz[r]);
                pp[r] = fmaf(hk, wp, pp[r]);
                qq[r] = fmaf(hk, wq, qq[r]);
            }
        }
#pragma unroll
        for (int r = 0; r < R; ++r) {
            if (n0 + r < N) {
                size_t o = (size_t)(n0 + r) * HID + lane;
                z[o] = zz[r]; p[o] = pp[r]; q[o] = qq[r];
            }
        }
    }
}

// --- per-XCD histogram: XCD x (=blockIdx%8) counts its edge chunk into cnt8[x][dst] ---
__global__ void k_hist8(const int* __restrict__ ei, int* __restrict__ cnt8, int E, int N) {
    int x  = blockIdx.x & 7;
    int o  = blockIdx.x >> 3;
    int Sx = gridDim.x >> 3;
    int CH = (E + 7) / 8;
    int e0 = x * CH;
    int e1 = min(e0 + CH, E);
    int* cx = cnt8 + (size_t)x * N;
    for (int e = e0 + o * 256 + (int)threadIdx.x; e < e1; e += Sx * 256)
        atomicAdd(&cx[ei[E + e]], 1);
}

// --- exclusive scan over M=8N elements, 16 per thread (4096/block) ---
__global__ void k_scan1(const int* __restrict__ cnt, int* __restrict__ rs,
                        int* __restrict__ bsum, int M) {
    __shared__ int lds[256];
    int t = threadIdx.x;
    int base = blockIdx.x * 4096 + t * 16;
    int v[16];
    if (base + 16 <= M) {
#pragma unroll
        for (int u = 0; u < 4; ++u) {
            int4 w = *reinterpret_cast<const int4*>(cnt + base + u * 4);
            v[u * 4 + 0] = w.x; v[u * 4 + 1] = w.y; v[u * 4 + 2] = w.z; v[u * 4 + 3] = w.w;
        }
    } else {
#pragma unroll
        for (int u = 0; u < 16; ++u) v[u] = (base + u < M) ? cnt[base + u] : 0;
    }
    int run = 0;
#pragma unroll
    for (int u = 0; u < 16; ++u) { int tv = v[u]; v[u] = run; run += tv; }
    lds[t] = run;
    __syncthreads();
#pragma unroll
    for (int off = 1; off < 256; off <<= 1) {
        int xw = (t >= off) ? lds[t - off] : 0;
        __syncthreads();
        lds[t] += xw;
        __syncthreads();
    }
    int excl = lds[t] - run;
    if (t == 255) bsum[blockIdx.x] = lds[255];
#pragma unroll
    for (int u = 0; u < 16; ++u)
        if (base + u < M) rs[base + u] = excl + v[u];
}

// rs[i] += exscan(bsum)[i>>12]; cur[i]=rs[i]; rs[M]=E
__global__ void k_scan_add(int* __restrict__ rs, int* __restrict__ cur,
                           const int* __restrict__ bsum, int NB, int M, int E) {
    __shared__ int lds[256];
    __shared__ int excl[256];
    int t = threadIdx.x;
    int v = (t < NB) ? bsum[t] : 0;
    lds[t] = v;
    __syncthreads();
#pragma unroll
    for (int off = 1; off < 256; off <<= 1) {
        int xw = (t >= off) ? lds[t - off] : 0;
        __syncthreads();
        lds[t] += xw;
        __syncthreads();
    }
    excl[t] = lds[t] - v;
    __syncthreads();
    int i = blockIdx.x * 256 + t;
    if (i < M) {
        int val = rs[i] + excl[i >> 12];
        rs[i] = val;
        cur[i] = val;
    }
    if (i == 0) rs[M] = E;
}

// --- per-XCD scatter into concatenated per-XCD dst-sorted lists ---
__global__ void k_scatter8(const int* __restrict__ ei, int* __restrict__ cur8,
                           int* __restrict__ csr8, int E, int N) {
    int x  = blockIdx.x & 7;
    int o  = blockIdx.x >> 3;
    int Sx = gridDim.x >> 3;
    int CH = (E + 7) / 8;
    int e0 = x * CH;
    int e1 = min(e0 + CH, E);
    int* cx = cur8 + (size_t)x * N;
    for (int e = e0 + o * 256 + (int)threadIdx.x; e < e1; e += Sx * 256) {
        int srcn = ei[e];
        int dstn = ei[E + e];
        int pos = atomicAdd(&cx[dstn], 1);
        csr8[pos] = srcn;
    }
}

// --- pure gather (8 segments per node) + elementwise epilogue ---
// Wave = 4 groups x 16 lanes; group g -> node n0+g; lane ql holds channels 4ql..4ql+3.
__global__ __launch_bounds__(256) void k_final(
    const float* __restrict__ z, const float* __restrict__ p, const float* __restrict__ q,
    const int* __restrict__ rs8f, const int* __restrict__ csr8,
    const float* __restrict__ W2, const float* __restrict__ b2,
    float* __restrict__ out, int N)
{
    int lane = threadIdx.x & 63;
    int g    = lane >> 4;
    int ql   = lane & 15;
    int wid  = (blockIdx.x * 256 + threadIdx.x) >> 6;
    int nw   = (gridDim.x * 256) >> 6;

    float4 w2v = *reinterpret_cast<const float4*>(W2 + 4 * ql);
    float b2s = b2[0];
    const float* zq = z + ql * 4;

    for (int n0 = wid * R; n0 < N; n0 += nw * R) {
        int ng   = n0 + g;
        bool okg = ng < N;

        // lanes 0..7 load seg-begin rs8f[x][ng]; lanes 8..15 load seg-end rs8f[x][ng+1]
        int rv = okg ? rs8f[(size_t)(ql & 7) * N + ng + (ql >> 3)] : 0;
        int bx[8], cum[8];
        int dsum = 0;
#pragma unroll
        for (int xx = 0; xx < 8; ++xx) {
            int bb = __shfl(rv, g * 16 + xx);
            int ee = __shfl(rv, g * 16 + 8 + xx);
            bx[xx] = bb;
            cum[xx] = dsum;
            dsum += (ee - bb);
        }
        int deg = dsum;

        float4 p4 = okg ? *reinterpret_cast<const float4*>(p + (size_t)ng * HID + 4 * ql)
                        : make_float4(0.f, 0.f, 0.f, 0.f);
        float4 q4 = okg ? *reinterpret_cast<const float4*>(q + (size_t)ng * HID + 4 * ql)
                        : make_float4(0.f, 0.f, 0.f, 0.f);

        int md = deg;
        md = max(md, __shfl_xor(md, 16));
        md = max(md, __shfl_xor(md, 32));

        float4 acc = {0.f, 0.f, 0.f, 0.f};
        for (int c = 0; c < md; c += 16) {
            int j = c + ql;
            // segment search: last x with cum[x] <= j
            int apos = bx[0] + j;
#pragma unroll
            for (int xx = 1; xx < 8; ++xx)
                apos = (j >= cum[xx]) ? (bx[xx] + (j - cum[xx])) : apos;
            int idxv = (j < deg) ? csr8[apos] : -1;
#pragma unroll
            for (int jb = 0; jb < 2; ++jb) {
                if (jb == 1 && md <= c + 8) break;
                int id[8];
#pragma unroll
                for (int u = 0; u < 8; ++u)
                    id[u] = __shfl(idxv, g * 16 + jb * 8 + u);
                float4 v[8];
#pragma unroll
                for (int u = 0; u < 8; ++u) {
                    int safe = (id[u] < 0) ? 0 : id[u];
                    v[u] = *reinterpret_cast<const float4*>(zq + (size_t)safe * HID);
                }
#pragma unroll
                for (int u = 0; u < 8; ++u) {
                    if (id[u] >= 0) {
                        acc.x += v[u].x; acc.y += v[u].y;
                        acc.z += v[u].z; acc.w += v[u].w;
                    }
                }
            }
        }

        float rcpd = 1.f / fmaxf((float)deg, 1.f);
        float flag = (deg > 0) ? 1.f : 0.f;
        float4 y;
        y.x = p4.x + flag * (acc.x * rcpd + q4.x);
        y.y = p4.y + flag * (acc.y * rcpd + q4.y);
        y.z = p4.z + flag * (acc.z * rcpd + q4.z);
        y.w = p4.w + flag * (acc.w * rcpd + q4.w);

        float part = fmaxf(y.x, 0.f) * w2v.x + fmaxf(y.y, 0.f) * w2v.y +
                     fmaxf(y.z, 0.f) * w2v.z + fmaxf(y.w, 0.f) * w2v.w;
#pragma unroll
        for (int off = 1; off < 16; off <<= 1) part += __shfl_xor(part, off);
        if (ql == 0 && okg) out[ng] = part + b2s;
    }
}

extern "C" void kernel_launch(void* const* d_in, const int* in_sizes, int n_in,
                              void* d_out, int out_size, void* d_ws, size_t ws_size,
                              hipStream_t stream) {
    const float* x   = (const float*)d_in[0];
    const int*   ei  = (const int*)d_in[1];
    const float* W0  = (const float*)d_in[2];
    const float* b0  = (const float*)d_in[3];
    const float* W1  = (const float*)d_in[4];
    const float* b1  = (const float*)d_in[5];
    const float* W2  = (const float*)d_in[6];
    const float* b2  = (const float*)d_in[7];
    const float* M0  = (const float*)d_in[8];
    const float* bM0 = (const float*)d_in[9];

    int N = in_sizes[0] / IN_C;
    int E = in_sizes[1] / 2;
    int M = 8 * N;
    int NB = (M + 4095) / 4096;   // <= 256 for N <= 131072

    float* z    = (float*)d_ws;                    // N*64
    float* p    = z + (size_t)N * HID;             // N*64
    float* q    = p + (size_t)N * HID;             // N*64
    int*   cnt8 = (int*)(q + (size_t)N * HID);     // 8N
    int*   rs8f = cnt8 + (size_t)M;                // 8N+1
    int*   cur8 = rs8f + (size_t)M + 1;            // 8N
    int*   bsum = cur8 + (size_t)M;                // 256
    float* WZ   = (float*)(bsum + 256);            // 4096
    float* WQ   = WZ + HID * HID;                  // 4096
    float* cb   = WQ + HID * HID;                  // 64
    int*   csr8 = (int*)(cb + HID);                // E
    float* out  = (float*)d_out;

    hipMemsetAsync(cnt8, 0, (size_t)M * sizeof(int), stream);
    k_wcomb<<<32, 256, 0, stream>>>(M0, W1, bM0, WZ, WQ, cb);
    k_node0pre<<<768, 256, 0, stream>>>(x, W0, b0, WZ, WQ, cb, W1, b1, z, p, q, N);
    k_hist8<<<800, 256, 0, stream>>>(ei, cnt8, E, N);
    k_scan1<<<NB, 256, 0, stream>>>(cnt8, rs8f, bsum, M);
    k_scan_add<<<(M + 255) / 256, 256, 0, stream>>>(rs8f, cur8, bsum, NB, M, E);
    k_scatter8<<<1600, 256, 0, stream>>>(ei, cur8, csr8, E, N);
    k_final<<<2048, 256, 0, stream>>>(z, p, q, rs8f, csr8, W2, b2, out, N);
}

// Round 8
// 246.729 us; speedup vs baseline: 1.7621x; 1.2069x over previous
//
#include <hip/hip_runtime.h>

#define HID 64
#define IN_C 16
#define R 4

typedef __attribute__((ext_vector_type(8))) short short8;
typedef __attribute__((ext_vector_type(4))) float f32x4;

// ---------------- weight packing: Wstack = [WZ | W1 | WQ] (64 x 192) ----------------
// WZ = Mt@W1, WQ = Mb@W1.  Packed into MFMA B-fragment layout, split bf16 hi/lo:
// frag (ct,s): B[k][n], lane l holds n=l&15, k=(l>>4)*8+j.  flat = ((ct*2+s)*64+l)*8+j
__global__ void k_wcomb2(const float* __restrict__ M0, const float* __restrict__ W1,
                         const float* __restrict__ bM0, const float* __restrict__ b1,
                         ushort* __restrict__ WPhi, ushort* __restrict__ WPlo,
                         float* __restrict__ bias192) {
    int tg = blockIdx.x * 256 + threadIdx.x;      // 0 .. 12287
    if (tg >= 64 * 192) return;
    int cc = tg % 192;
    int k  = tg / 192;
    float w;
    if (cc < 64) {
        float acc = 0.f;
#pragma unroll
        for (int m = 0; m < HID; ++m) acc = fmaf(M0[k * HID + m], W1[m * HID + cc], acc);
        w = acc;
    } else if (cc < 128) {
        w = W1[k * HID + (cc - 64)];
    } else {
        float acc = 0.f;
#pragma unroll
        for (int m = 0; m < HID; ++m) acc = fmaf(M0[(HID + k) * HID + m], W1[m * HID + (cc - 128)], acc);
        w = acc;
    }
    unsigned wb = __float_as_uint(w);
    ushort hi = (ushort)(wb >> 16);
    float hif = __uint_as_float(wb & 0xffff0000u);
    ushort lo = (ushort)(__float_as_uint(w - hif) >> 16);
    int ct = cc >> 4, s = k >> 5, l = ((k >> 3) & 3) * 16 + (cc & 15), j = k & 7;
    int fi = ((ct * 2 + s) * 64 + l) * 8 + j;
    WPhi[fi] = hi;
    WPlo[fi] = lo;
    if (k == 0) {
        float bv;
        if (cc < 64) bv = 0.f;
        else if (cc < 128) bv = b1[cc - 64];
        else {
            float acc = 0.f;
#pragma unroll
            for (int m = 0; m < HID; ++m) acc = fmaf(bM0[m], W1[m * HID + (cc - 128)], acc);
            bv = acc;
        }
        bias192[cc] = bv;
    }
}

// ---------------- MFMA precompute: h=relu(x@W0+b0); [z|p|q] = h @ Wstack + bias ----------------
// Block = 4 waves = 64 nodes.  Wave w: computes h for nodes [n0+16w, +16) into swizzled
// LDS (bf16 hi/lo), then owns column-tiles {3w,3w+1,3w+2} with B-frags in registers.
__global__ __launch_bounds__(256) void k_pre_mfma(
    const float* __restrict__ x, const float* __restrict__ W0, const float* __restrict__ b0,
    const ushort* __restrict__ WPhi, const ushort* __restrict__ WPlo,
    const float* __restrict__ bias192,
    float* __restrict__ z, float* __restrict__ p, float* __restrict__ q, int N)
{
    __shared__ ushort hhi[64 * 64];
    __shared__ ushort hlo[64 * 64];

    int tid  = threadIdx.x;
    int lane = tid & 63;
    int w    = tid >> 6;          // wave 0..3
    int n0   = blockIdx.x * 64;

    // W0 column + bias, register-hoisted
    float w0c[IN_C];
#pragma unroll
    for (int k = 0; k < IN_C; ++k) w0c[k] = W0[k * HID + lane];
    float b0l = b0[lane];

    // B-fragments for this wave's 3 column-tiles (held in registers)
    short8 Bhi[3][2], Blo[3][2];
    float bias[3];
#pragma unroll
    for (int i = 0; i < 3; ++i) {
        int ct = w * 3 + i;
#pragma unroll
        for (int s = 0; s < 2; ++s) {
            int fi = ((ct * 2 + s) * 64 + lane) * 8;
            Bhi[i][s] = *reinterpret_cast<const short8*>(WPhi + fi);
            Blo[i][s] = *reinterpret_cast<const short8*>(WPlo + fi);
        }
        bias[i] = bias192[ct * 16 + (lane & 15)];
    }

    // phase 1: h for 16 nodes (lane = channel), split bf16, swizzled LDS write
    for (int nn = 0; nn < 16; ++nn) {
        int n = n0 + w * 16 + nn;
        float acc = b0l;
        if (n < N) {
            const float* xr = x + (size_t)n * IN_C;
            float xv[IN_C];
#pragma unroll
            for (int u = 0; u < 4; ++u) {
                float4 t = *reinterpret_cast<const float4*>(xr + u * 4);
                xv[u * 4 + 0] = t.x; xv[u * 4 + 1] = t.y; xv[u * 4 + 2] = t.z; xv[u * 4 + 3] = t.w;
            }
#pragma unroll
            for (int k = 0; k < IN_C; ++k) acc = fmaf(xv[k], w0c[k], acc);
        }
        float h = fmaxf(acc, 0.f);
        unsigned hb = __float_as_uint(h);
        ushort hi = (ushort)(hb >> 16);
        float hif = __uint_as_float(hb & 0xffff0000u);
        ushort lo = (ushort)(__float_as_uint(h - hif) >> 16);
        int nl = w * 16 + nn;
        int u  = ((lane >> 3) ^ (nl & 7));
        int off = nl * 64 + u * 8 + (lane & 7);
        hhi[off] = hi;
        hlo[off] = lo;
    }
    __syncthreads();

    // phase 2: 4 node-subtiles x 3 cTiles x (2 ksteps x 4 split-terms) MFMA
#pragma unroll
    for (int st = 0; st < 4; ++st) {
        int nloc = st * 16 + (lane & 15);
        short8 Ahi[2], Alo[2];
#pragma unroll
        for (int s = 0; s < 2; ++s) {
            int u = (s * 4 + (lane >> 4)) ^ (nloc & 7);
            int off = nloc * 64 + u * 8;
            Ahi[s] = *reinterpret_cast<const short8*>(hhi + off);
            Alo[s] = *reinterpret_cast<const short8*>(hlo + off);
        }
#pragma unroll
        for (int i = 0; i < 3; ++i) {
            int ct = w * 3 + i;
            f32x4 acc = {bias[i], bias[i], bias[i], bias[i]};
#pragma unroll
            for (int s = 0; s < 2; ++s) {
                acc = __builtin_amdgcn_mfma_f32_16x16x32_bf16(Ahi[s], Bhi[i][s], acc, 0, 0, 0);
                acc = __builtin_amdgcn_mfma_f32_16x16x32_bf16(Ahi[s], Blo[i][s], acc, 0, 0, 0);
                acc = __builtin_amdgcn_mfma_f32_16x16x32_bf16(Alo[s], Bhi[i][s], acc, 0, 0, 0);
                acc = __builtin_amdgcn_mfma_f32_16x16x32_bf16(Alo[s], Blo[i][s], acc, 0, 0, 0);
            }
            int ch = ct * 16 + (lane & 15);
            float* dst; int c;
            if (ch < 64)       { dst = z; c = ch; }
            else if (ch < 128) { dst = p; c = ch - 64; }
            else               { dst = q; c = ch - 128; }
#pragma unroll
            for (int r = 0; r < 4; ++r) {
                int n = n0 + st * 16 + (lane >> 4) * 4 + r;
                if (n < N) dst[(size_t)n * HID + c] = acc[r];
            }
        }
    }
}

// --- per-XCD histogram: XCD x (=blockIdx%8) counts its edge chunk into cnt8[x][dst] ---
__global__ void k_hist8(const int* __restrict__ ei, int* __restrict__ cnt8, int E, int N) {
    int x  = blockIdx.x & 7;
    int o  = blockIdx.x >> 3;
    int Sx = gridDim.x >> 3;
    int CH = (E + 7) / 8;
    int e0 = x * CH;
    int e1 = min(e0 + CH, E);
    int* cx = cnt8 + (size_t)x * N;
    for (int e = e0 + o * 256 + (int)threadIdx.x; e < e1; e += Sx * 256)
        atomicAdd(&cx[ei[E + e]], 1);
}

// --- exclusive scan over M=8N elements, 16 per thread (4096/block) ---
__global__ void k_scan1(const int* __restrict__ cnt, int* __restrict__ rs,
                        int* __restrict__ bsum, int M) {
    __shared__ int lds[256];
    int t = threadIdx.x;
    int base = blockIdx.x * 4096 + t * 16;
    int v[16];
    if (base + 16 <= M) {
#pragma unroll
        for (int u = 0; u < 4; ++u) {
            int4 w = *reinterpret_cast<const int4*>(cnt + base + u * 4);
            v[u * 4 + 0] = w.x; v[u * 4 + 1] = w.y; v[u * 4 + 2] = w.z; v[u * 4 + 3] = w.w;
        }
    } else {
#pragma unroll
        for (int u = 0; u < 16; ++u) v[u] = (base + u < M) ? cnt[base + u] : 0;
    }
    int run = 0;
#pragma unroll
    for (int u = 0; u < 16; ++u) { int tv = v[u]; v[u] = run; run += tv; }
    lds[t] = run;
    __syncthreads();
#pragma unroll
    for (int off = 1; off < 256; off <<= 1) {
        int xw = (t >= off) ? lds[t - off] : 0;
        __syncthreads();
        lds[t] += xw;
        __syncthreads();
    }
    int excl = lds[t] - run;
    if (t == 255) bsum[blockIdx.x] = lds[255];
#pragma unroll
    for (int u = 0; u < 16; ++u)
        if (base + u < M) rs[base + u] = excl + v[u];
}

// rs[i] += exscan(bsum)[i>>12]; cur[i]=rs[i]; rs[M]=E
__global__ void k_scan_add(int* __restrict__ rs, int* __restrict__ cur,
                           const int* __restrict__ bsum, int NB, int M, int E) {
    __shared__ int lds[256];
    __shared__ int excl[256];
    int t = threadIdx.x;
    int v = (t < NB) ? bsum[t] : 0;
    lds[t] = v;
    __syncthreads();
#pragma unroll
    for (int off = 1; off < 256; off <<= 1) {
        int xw = (t >= off) ? lds[t - off] : 0;
        __syncthreads();
        lds[t] += xw;
        __syncthreads();
    }
    excl[t] = lds[t] - v;
    __syncthreads();
    int i = blockIdx.x * 256 + t;
    if (i < M) {
        int val = rs[i] + excl[i >> 12];
        rs[i] = val;
        cur[i] = val;
    }
    if (i == 0) rs[M] = E;
}

// --- per-XCD scatter into concatenated per-XCD dst-sorted lists ---
__global__ void k_scatter8(const int* __restrict__ ei, int* __restrict__ cur8,
                           int* __restrict__ csr8, int E, int N) {
    int x  = blockIdx.x & 7;
    int o  = blockIdx.x >> 3;
    int Sx = gridDim.x >> 3;
    int CH = (E + 7) / 8;
    int e0 = x * CH;
    int e1 = min(e0 + CH, E);
    int* cx = cur8 + (size_t)x * N;
    for (int e = e0 + o * 256 + (int)threadIdx.x; e < e1; e += Sx * 256) {
        int srcn = ei[e];
        int dstn = ei[E + e];
        int pos = atomicAdd(&cx[dstn], 1);
        csr8[pos] = srcn;
    }
}

// --- pure gather (8 segments per node) + elementwise epilogue ---
__global__ __launch_bounds__(256) void k_final(
    const float* __restrict__ z, const float* __restrict__ p, const float* __restrict__ q,
    const int* __restrict__ rs8f, const int* __restrict__ csr8,
    const float* __restrict__ W2, const float* __restrict__ b2,
    float* __restrict__ out, int N)
{
    int lane = threadIdx.x & 63;
    int g    = lane >> 4;
    int ql   = lane & 15;
    int wid  = (blockIdx.x * 256 + threadIdx.x) >> 6;
    int nw   = (gridDim.x * 256) >> 6;

    float4 w2v = *reinterpret_cast<const float4*>(W2 + 4 * ql);
    float b2s = b2[0];
    const float* zq = z + ql * 4;

    for (int n0 = wid * R; n0 < N; n0 += nw * R) {
        int ng   = n0 + g;
        bool okg = ng < N;

        int rv = okg ? rs8f[(size_t)(ql & 7) * N + ng + (ql >> 3)] : 0;
        int bx[8], cum[8];
        int dsum = 0;
#pragma unroll
        for (int xx = 0; xx < 8; ++xx) {
            int bb = __shfl(rv, g * 16 + xx);
            int ee = __shfl(rv, g * 16 + 8 + xx);
            bx[xx] = bb;
            cum[xx] = dsum;
            dsum += (ee - bb);
        }
        int deg = dsum;

        float4 p4 = okg ? *reinterpret_cast<const float4*>(p + (size_t)ng * HID + 4 * ql)
                        : make_float4(0.f, 0.f, 0.f, 0.f);
        float4 q4 = okg ? *reinterpret_cast<const float4*>(q + (size_t)ng * HID + 4 * ql)
                        : make_float4(0.f, 0.f, 0.f, 0.f);

        int md = deg;
        md = max(md, __shfl_xor(md, 16));
        md = max(md, __shfl_xor(md, 32));

        float4 acc = {0.f, 0.f, 0.f, 0.f};
        for (int c = 0; c < md; c += 16) {
            int j = c + ql;
            int apos = bx[0] + j;
#pragma unroll
            for (int xx = 1; xx < 8; ++xx)
                apos = (j >= cum[xx]) ? (bx[xx] + (j - cum[xx])) : apos;
            int idxv = (j < deg) ? csr8[apos] : -1;
#pragma unroll
            for (int jb = 0; jb < 2; ++jb) {
                if (jb == 1 && md <= c + 8) break;
                int id[8];
#pragma unroll
                for (int u = 0; u < 8; ++u)
                    id[u] = __shfl(idxv, g * 16 + jb * 8 + u);
                float4 v[8];
#pragma unroll
                for (int u = 0; u < 8; ++u) {
                    int safe = (id[u] < 0) ? 0 : id[u];
                    v[u] = *reinterpret_cast<const float4*>(zq + (size_t)safe * HID);
                }
#pragma unroll
                for (int u = 0; u < 8; ++u) {
                    if (id[u] >= 0) {
                        acc.x += v[u].x; acc.y += v[u].y;
                        acc.z += v[u].z; acc.w += v[u].w;
                    }
                }
            }
        }

        float rcpd = 1.f / fmaxf((float)deg, 1.f);
        float flag = (deg > 0) ? 1.f : 0.f;
        float4 y;
        y.x = p4.x + flag * (acc.x * rcpd + q4.x);
        y.y = p4.y + flag * (acc.y * rcpd + q4.y);
        y.z = p4.z + flag * (acc.z * rcpd + q4.z);
        y.w = p4.w + flag * (acc.w * rcpd + q4.w);

        float part = fmaxf(y.x, 0.f) * w2v.x + fmaxf(y.y, 0.f) * w2v.y +
                     fmaxf(y.z, 0.f) * w2v.z + fmaxf(y.w, 0.f) * w2v.w;
#pragma unroll
        for (int off = 1; off < 16; off <<= 1) part += __shfl_xor(part, off);
        if (ql == 0 && okg) out[ng] = part + b2s;
    }
}

extern "C" void kernel_launch(void* const* d_in, const int* in_sizes, int n_in,
                              void* d_out, int out_size, void* d_ws, size_t ws_size,
                              hipStream_t stream) {
    const float* x   = (const float*)d_in[0];
    const int*   ei  = (const int*)d_in[1];
    const float* W0  = (const float*)d_in[2];
    const float* b0  = (const float*)d_in[3];
    const float* W1  = (const float*)d_in[4];
    const float* b1  = (const float*)d_in[5];
    const float* W2  = (const float*)d_in[6];
    const float* b2  = (const float*)d_in[7];
    const float* M0  = (const float*)d_in[8];
    const float* bM0 = (const float*)d_in[9];

    int N = in_sizes[0] / IN_C;
    int E = in_sizes[1] / 2;
    int M = 8 * N;
    int NB = (M + 4095) / 4096;   // <= 256 for N <= 131072

    float*  z      = (float*)d_ws;                    // N*64
    float*  p      = z + (size_t)N * HID;             // N*64
    float*  q      = p + (size_t)N * HID;             // N*64
    int*    cnt8   = (int*)(q + (size_t)N * HID);     // 8N
    ushort* WPhi   = (ushort*)(cnt8 + (size_t)M);     // 12288 (16B-aligned)
    ushort* WPlo   = WPhi + 12288;                    // 12288
    float*  bias192= (float*)(WPlo + 12288);          // 192
    int*    rs8f   = (int*)(bias192 + 192);           // 8N+1
    int*    cur8   = rs8f + (size_t)M + 1;            // 8N
    int*    bsum   = cur8 + (size_t)M;                // 256
    int*    csr8   = bsum + 256;                      // E
    float*  out    = (float*)d_out;

    hipMemsetAsync(cnt8, 0, (size_t)M * sizeof(int), stream);
    k_wcomb2<<<48, 256, 0, stream>>>(M0, W1, bM0, b1, WPhi, WPlo, bias192);
    k_pre_mfma<<<(N + 63) / 64, 256, 0, stream>>>(x, W0, b0, WPhi, WPlo, bias192, z, p, q, N);
    k_hist8<<<800, 256, 0, stream>>>(ei, cnt8, E, N);
    k_scan1<<<NB, 256, 0, stream>>>(cnt8, rs8f, bsum, M);
    k_scan_add<<<(M + 255) / 256, 256, 0, stream>>>(rs8f, cur8, bsum, NB, M, E);
    k_scatter8<<<1600, 256, 0, stream>>>(ei, cur8, csr8, E, N);
    k_final<<<2048, 256, 0, stream>>>(z, p, q, rs8f, csr8, W2, b2, out, N);
}

// Round 9
// 212.597 us; speedup vs baseline: 2.0450x; 1.1605x over previous
//
#include <hip/hip_runtime.h>

#define HID 64
#define IN_C 16

typedef __attribute__((ext_vector_type(8))) short short8;
typedef __attribute__((ext_vector_type(4))) float f32x4;

__device__ __forceinline__ float bitsf(unsigned u) { return __uint_as_float(u); }

// ---- k_init: zero cnt8 + pack stacked weights [WZ | W1+WQ | W1] into MFMA B-frags ----
// WZ = Mt@W1 (bias 0), WPQ = W1 + Mb@W1 (bias b1 + bM0@W1), P-tile = W1 (bias b1).
// frag (ct,s): B[k][n], lane l holds n=l&15, k=(l>>4)*8+j; flat = ((ct*2+s)*64+l)*8+j
__global__ void k_init(const float* __restrict__ M0, const float* __restrict__ W1,
                       const float* __restrict__ bM0, const float* __restrict__ b1,
                       int* __restrict__ cnt8, int M4,
                       ushort* __restrict__ WPhi, ushort* __restrict__ WPlo,
                       float* __restrict__ bias192) {
    int tid = blockIdx.x * 256 + threadIdx.x;
    int stride = gridDim.x * 256;
    int4 z4 = {0, 0, 0, 0};
    for (int i = tid; i < M4; i += stride) reinterpret_cast<int4*>(cnt8)[i] = z4;

    if (tid < 64 * 192) {
        int cc = tid % 192;
        int k  = tid / 192;
        float w;
        if (cc < 64) {
            float a = 0.f;
#pragma unroll
            for (int m = 0; m < HID; ++m) a = fmaf(M0[k * HID + m], W1[m * HID + cc], a);
            w = a;
        } else if (cc < 128) {
            int c = cc - 64;
            float a = W1[k * HID + c];
#pragma unroll
            for (int m = 0; m < HID; ++m) a = fmaf(M0[(HID + k) * HID + m], W1[m * HID + c], a);
            w = a;
        } else {
            w = W1[k * HID + (cc - 128)];
        }
        unsigned wb = __float_as_uint(w);
        ushort hi = (ushort)(wb >> 16);
        float hif = __uint_as_float(wb & 0xffff0000u);
        ushort lo = (ushort)(__float_as_uint(w - hif) >> 16);
        int ct = cc >> 4, s = k >> 5, l = ((k >> 3) & 3) * 16 + (cc & 15), j = k & 7;
        int fi = ((ct * 2 + s) * 64 + l) * 8 + j;
        WPhi[fi] = hi;
        WPlo[fi] = lo;
        if (k == 0) {
            float bv;
            if (cc < 64) bv = 0.f;
            else if (cc < 128) {
                int c = cc - 64;
                float a = b1[c];
#pragma unroll
                for (int m = 0; m < HID; ++m) a = fmaf(bM0[m], W1[m * HID + c], a);
                bv = a;
            } else bv = b1[cc - 128];
            bias192[cc] = bv;
        }
    }
}

// ---- fused: [blocks < nbh] per-XCD histogram ; [blocks >= nbh] MFMA precompute ----
// pre: h=relu(x@W0+b0) -> split bf16 LDS -> [zb(bf16) | PQ | P] = h @ Wstack + bias
__global__ __launch_bounds__(256) void k_pre_hist(
    const float* __restrict__ x, const float* __restrict__ W0, const float* __restrict__ b0,
    const ushort* __restrict__ WPhi, const ushort* __restrict__ WPlo,
    const float* __restrict__ bias192,
    ushort* __restrict__ zb, float* __restrict__ PQ, float* __restrict__ Pp, int N,
    const int* __restrict__ ei, int* __restrict__ cnt8, int E, int nbh)
{
    __shared__ ushort hhi[64 * 64];
    __shared__ ushort hlo[64 * 64];

    if ((int)blockIdx.x < nbh) {
        int xc = blockIdx.x & 7;
        int o  = blockIdx.x >> 3;
        int Sx = nbh >> 3;
        int CH = (E + 7) / 8;
        int e0 = xc * CH;
        int e1 = min(e0 + CH, E);
        int* cx = cnt8 + (size_t)xc * N;
        for (int e = e0 + o * 256 + (int)threadIdx.x; e < e1; e += Sx * 256)
            atomicAdd(&cx[ei[E + e]], 1);
        return;
    }

    int tid  = threadIdx.x;
    int lane = tid & 63;
    int w    = tid >> 6;
    int n0   = (blockIdx.x - nbh) * 64;

    float w0c[IN_C];
#pragma unroll
    for (int k = 0; k < IN_C; ++k) w0c[k] = W0[k * HID + lane];
    float b0l = b0[lane];

    short8 Bhi[3][2], Blo[3][2];
    float bias[3];
#pragma unroll
    for (int i = 0; i < 3; ++i) {
        int ct = w * 3 + i;
#pragma unroll
        for (int s = 0; s < 2; ++s) {
            int fi = ((ct * 2 + s) * 64 + lane) * 8;
            Bhi[i][s] = *reinterpret_cast<const short8*>(WPhi + fi);
            Blo[i][s] = *reinterpret_cast<const short8*>(WPlo + fi);
        }
        bias[i] = bias192[ct * 16 + (lane & 15)];
    }

    // phase 1: h for 16 nodes, split bf16, swizzled LDS
    for (int nn = 0; nn < 16; ++nn) {
        int n = n0 + w * 16 + nn;
        float acc = b0l;
        if (n < N) {
            const float* xr = x + (size_t)n * IN_C;
            float xv[IN_C];
#pragma unroll
            for (int u = 0; u < 4; ++u) {
                float4 t = *reinterpret_cast<const float4*>(xr + u * 4);
                xv[u * 4 + 0] = t.x; xv[u * 4 + 1] = t.y; xv[u * 4 + 2] = t.z; xv[u * 4 + 3] = t.w;
            }
#pragma unroll
            for (int k = 0; k < IN_C; ++k) acc = fmaf(xv[k], w0c[k], acc);
        }
        float h = fmaxf(acc, 0.f);
        unsigned hb = __float_as_uint(h);
        ushort hi = (ushort)(hb >> 16);
        float hif = __uint_as_float(hb & 0xffff0000u);
        ushort lo = (ushort)(__float_as_uint(h - hif) >> 16);
        int nl = w * 16 + nn;
        int u  = ((lane >> 3) ^ (nl & 7));
        int off = nl * 64 + u * 8 + (lane & 7);
        hhi[off] = hi;
        hlo[off] = lo;
    }
    __syncthreads();

    // phase 2: MFMA
#pragma unroll
    for (int st = 0; st < 4; ++st) {
        int nloc = st * 16 + (lane & 15);
        short8 Ahi[2], Alo[2];
#pragma unroll
        for (int s = 0; s < 2; ++s) {
            int u = (s * 4 + (lane >> 4)) ^ (nloc & 7);
            int off = nloc * 64 + u * 8;
            Ahi[s] = *reinterpret_cast<const short8*>(hhi + off);
            Alo[s] = *reinterpret_cast<const short8*>(hlo + off);
        }
#pragma unroll
        for (int i = 0; i < 3; ++i) {
            int ct = w * 3 + i;
            f32x4 acc = {bias[i], bias[i], bias[i], bias[i]};
#pragma unroll
            for (int s = 0; s < 2; ++s) {
                acc = __builtin_amdgcn_mfma_f32_16x16x32_bf16(Ahi[s], Bhi[i][s], acc, 0, 0, 0);
                acc = __builtin_amdgcn_mfma_f32_16x16x32_bf16(Ahi[s], Blo[i][s], acc, 0, 0, 0);
                acc = __builtin_amdgcn_mfma_f32_16x16x32_bf16(Alo[s], Bhi[i][s], acc, 0, 0, 0);
                acc = __builtin_amdgcn_mfma_f32_16x16x32_bf16(Alo[s], Blo[i][s], acc, 0, 0, 0);
            }
            int ch = ct * 16 + (lane & 15);
#pragma unroll
            for (int r = 0; r < 4; ++r) {
                int n = n0 + st * 16 + (lane >> 4) * 4 + r;
                if (n >= N) continue;
                float v = acc[r];
                if (ch < 64) {
                    unsigned u = __float_as_uint(v);
                    unsigned rr = (u + 0x7fffu + ((u >> 16) & 1u)) >> 16;
                    zb[(size_t)n * HID + ch] = (ushort)rr;
                } else if (ch < 128) {
                    PQ[(size_t)n * HID + (ch - 64)] = v;
                } else {
                    Pp[(size_t)n * HID + (ch - 128)] = v;
                }
            }
        }
    }
}

// ---- exclusive scan over M=8N elements, 16 per thread (4096/block) ----
__global__ void k_scan1(const int* __restrict__ cnt, int* __restrict__ rs,
                        int* __restrict__ bsum, int M) {
    __shared__ int lds[256];
    int t = threadIdx.x;
    int base = blockIdx.x * 4096 + t * 16;
    int v[16];
    if (base + 16 <= M) {
#pragma unroll
        for (int u = 0; u < 4; ++u) {
            int4 w = *reinterpret_cast<const int4*>(cnt + base + u * 4);
            v[u * 4 + 0] = w.x; v[u * 4 + 1] = w.y; v[u * 4 + 2] = w.z; v[u * 4 + 3] = w.w;
        }
    } else {
#pragma unroll
        for (int u = 0; u < 16; ++u) v[u] = (base + u < M) ? cnt[base + u] : 0;
    }
    int run = 0;
#pragma unroll
    for (int u = 0; u < 16; ++u) { int tv = v[u]; v[u] = run; run += tv; }
    lds[t] = run;
    __syncthreads();
#pragma unroll
    for (int off = 1; off < 256; off <<= 1) {
        int xw = (t >= off) ? lds[t - off] : 0;
        __syncthreads();
        lds[t] += xw;
        __syncthreads();
    }
    int excl = lds[t] - run;
    if (t == 255) bsum[blockIdx.x] = lds[255];
#pragma unroll
    for (int u = 0; u < 16; ++u)
        if (base + u < M) rs[base + u] = excl + v[u];
}

// rs[i] += exscan(bsum)[i>>12]; cur[i]=rs[i]; rs[M]=E
__global__ void k_scan_add(int* __restrict__ rs, int* __restrict__ cur,
                           const int* __restrict__ bsum, int NB, int M, int E) {
    __shared__ int lds[256];
    __shared__ int excl[256];
    int t = threadIdx.x;
    int v = (t < NB) ? bsum[t] : 0;
    lds[t] = v;
    __syncthreads();
#pragma unroll
    for (int off = 1; off < 256; off <<= 1) {
        int xw = (t >= off) ? lds[t - off] : 0;
        __syncthreads();
        lds[t] += xw;
        __syncthreads();
    }
    excl[t] = lds[t] - v;
    __syncthreads();
    int i = blockIdx.x * 256 + t;
    if (i < M) {
        int val = rs[i] + excl[i >> 12];
        rs[i] = val;
        cur[i] = val;
    }
    if (i == 0) rs[M] = E;
}

// ---- per-XCD scatter into concatenated per-XCD dst-sorted lists ----
__global__ void k_scatter8(const int* __restrict__ ei, int* __restrict__ cur8,
                           int* __restrict__ csr8, int E, int N) {
    int xc = blockIdx.x & 7;
    int o  = blockIdx.x >> 3;
    int Sx = gridDim.x >> 3;
    int CH = (E + 7) / 8;
    int e0 = xc * CH;
    int e1 = min(e0 + CH, E);
    int* cx = cur8 + (size_t)xc * N;
    for (int e = e0 + o * 256 + (int)threadIdx.x; e < e1; e += Sx * 256) {
        int srcn = ei[e];
        int dstn = ei[E + e];
        int pos = atomicAdd(&cx[dstn], 1);
        csr8[pos] = srcn;
    }
}

// ---- bf16 gather (2 edges/round per 16-lane group) + elementwise epilogue ----
// group g -> node n0+g; lane: oct=ql&7 (channel octet), half=ql>>3 (edge parity).
__global__ __launch_bounds__(256) void k_final(
    const ushort* __restrict__ zb, const float* __restrict__ PQ, const float* __restrict__ Pp,
    const int* __restrict__ rs8f, const int* __restrict__ csr8,
    const float* __restrict__ W2, const float* __restrict__ b2,
    float* __restrict__ out, int N)
{
    int lane = threadIdx.x & 63;
    int g    = lane >> 4;
    int ql   = lane & 15;
    int oct  = ql & 7;
    int half = ql >> 3;
    int wid  = (blockIdx.x * 256 + threadIdx.x) >> 6;
    int nw   = (gridDim.x * 256) >> 6;

    int c0 = oct * 8 + half * 4;
    float4 w2v = *reinterpret_cast<const float4*>(W2 + c0);
    float b2s = b2[0];

    for (int n0 = wid * 4; n0 < N; n0 += nw * 4) {
        int ng   = n0 + g;
        bool okg = ng < N;

        // lanes ql<8 load seg-begin rs8f[oct][ng]; ql>=8 load seg-end
        int rv = okg ? rs8f[(size_t)oct * N + ng + half] : 0;
        int bx[8], cum[8];
        int dsum = 0;
#pragma unroll
        for (int xx = 0; xx < 8; ++xx) {
            int bb = __shfl(rv, g * 16 + xx);
            int ee = __shfl(rv, g * 16 + 8 + xx);
            bx[xx] = bb;
            cum[xx] = dsum;
            dsum += (ee - bb);
        }
        int deg = dsum;
        int md = deg;
        md = max(md, __shfl_xor(md, 16));
        md = max(md, __shfl_xor(md, 32));

        float acc[8];
#pragma unroll
        for (int i = 0; i < 8; ++i) acc[i] = 0.f;

        for (int c = 0; c < md; c += 32) {
            int j0 = c + ql, j1 = c + 16 + ql;
            int a0 = bx[0] + j0, a1 = bx[0] + j1;
#pragma unroll
            for (int xx = 1; xx < 8; ++xx) {
                a0 = (j0 >= cum[xx]) ? (bx[xx] + (j0 - cum[xx])) : a0;
                a1 = (j1 >= cum[xx]) ? (bx[xx] + (j1 - cum[xx])) : a1;
            }
            int ia = (j0 < deg) ? csr8[a0] : -1;
            int ib = (j1 < deg) ? csr8[a1] : -1;
#pragma unroll
            for (int tb = 0; tb < 4; ++tb) {
                if (tb > 0 && md <= c + 8 * tb) break;
                int srcs[4];
#pragma unroll
                for (int t4 = 0; t4 < 4; ++t4) {
                    int t = tb * 4 + t4;
                    int e = 2 * t + half;
                    srcs[t4] = __shfl(tb < 2 ? ia : ib, g * 16 + (e & 15));
                }
                uint4 rw[4];
#pragma unroll
                for (int t4 = 0; t4 < 4; ++t4) {
                    int s = srcs[t4] < 0 ? 0 : srcs[t4];
                    rw[t4] = *reinterpret_cast<const uint4*>(zb + (size_t)s * HID + oct * 8);
                }
#pragma unroll
                for (int t4 = 0; t4 < 4; ++t4) {
                    if (srcs[t4] >= 0) {
                        uint4 wv = rw[t4];
                        acc[0] += bitsf(wv.x << 16); acc[1] += bitsf(wv.x & 0xffff0000u);
                        acc[2] += bitsf(wv.y << 16); acc[3] += bitsf(wv.y & 0xffff0000u);
                        acc[4] += bitsf(wv.z << 16); acc[5] += bitsf(wv.z & 0xffff0000u);
                        acc[6] += bitsf(wv.w << 16); acc[7] += bitsf(wv.w & 0xffff0000u);
                    }
                }
            }
        }
#pragma unroll
        for (int i = 0; i < 8; ++i) acc[i] += __shfl_xor(acc[i], 8);

        float s0 = half ? acc[4] : acc[0];
        float s1 = half ? acc[5] : acc[1];
        float s2 = half ? acc[6] : acc[2];
        float s3 = half ? acc[7] : acc[3];

        float4 base = make_float4(0.f, 0.f, 0.f, 0.f);
        if (okg) {
            base = *reinterpret_cast<const float4*>(PQ + (size_t)ng * HID + c0);
            if (deg == 0)
                base = *reinterpret_cast<const float4*>(Pp + (size_t)ng * HID + c0);
        }
        float rcpd = (deg > 0) ? (1.f / (float)deg) : 0.f;
        float y0 = base.x + s0 * rcpd;
        float y1 = base.y + s1 * rcpd;
        float y2 = base.z + s2 * rcpd;
        float y3 = base.w + s3 * rcpd;

        float part = fmaxf(y0, 0.f) * w2v.x + fmaxf(y1, 0.f) * w2v.y +
                     fmaxf(y2, 0.f) * w2v.z + fmaxf(y3, 0.f) * w2v.w;
#pragma unroll
        for (int off = 1; off < 16; off <<= 1) part += __shfl_xor(part, off);
        if (ql == 0 && okg) out[ng] = part + b2s;
    }
}

extern "C" void kernel_launch(void* const* d_in, const int* in_sizes, int n_in,
                              void* d_out, int out_size, void* d_ws, size_t ws_size,
                              hipStream_t stream) {
    const float* x   = (const float*)d_in[0];
    const int*   ei  = (const int*)d_in[1];
    const float* W0  = (const float*)d_in[2];
    const float* b0  = (const float*)d_in[3];
    const float* W1  = (const float*)d_in[4];
    const float* b1  = (const float*)d_in[5];
    const float* W2  = (const float*)d_in[6];
    const float* b2  = (const float*)d_in[7];
    const float* M0  = (const float*)d_in[8];
    const float* bM0 = (const float*)d_in[9];

    int N = in_sizes[0] / IN_C;
    int E = in_sizes[1] / 2;
    int M = 8 * N;
    int NB = (M + 4095) / 4096;   // <= 256 for N <= 131072

    ushort* zb     = (ushort*)d_ws;                   // N*64 bf16
    float*  PQ     = (float*)(zb + (size_t)N * HID);  // N*64
    float*  Pp     = PQ + (size_t)N * HID;            // N*64
    ushort* WPhi   = (ushort*)(Pp + (size_t)N * HID); // 12288
    ushort* WPlo   = WPhi + 12288;                    // 12288
    float*  bias192= (float*)(WPlo + 12288);          // 192
    int*    cnt8   = (int*)(bias192 + 192);           // 8N
    int*    rs8f   = cnt8 + (size_t)M;                // 8N+1
    int*    cur8   = rs8f + (size_t)M + 1;            // 8N
    int*    bsum   = cur8 + (size_t)M;                // 256
    int*    csr8   = bsum + 256;                      // E
    float*  out    = (float*)d_out;

    int nbh  = 800;
    int npre = (N + 63) / 64;

    k_init<<<128, 256, 0, stream>>>(M0, W1, bM0, b1, cnt8, M / 4, WPhi, WPlo, bias192);
    k_pre_hist<<<nbh + npre, 256, 0, stream>>>(x, W0, b0, WPhi, WPlo, bias192,
                                               zb, PQ, Pp, N, ei, cnt8, E, nbh);
    k_scan1<<<NB, 256, 0, stream>>>(cnt8, rs8f, bsum, M);
    k_scan_add<<<(M + 255) / 256, 256, 0, stream>>>(rs8f, cur8, bsum, NB, M, E);
    k_scatter8<<<1600, 256, 0, stream>>>(ei, cur8, csr8, E, N);
    k_final<<<2048, 256, 0, stream>>>(zb, PQ, Pp, rs8f, csr8, W2, b2, out, N);
}

// Round 10
// 174.764 us; speedup vs baseline: 2.4877x; 1.2165x over previous
//
#include <hip/hip_runtime.h>

#define HID 64
#define IN_C 16

typedef __attribute__((ext_vector_type(8))) short short8;
typedef __attribute__((ext_vector_type(4))) float f32x4;

__device__ __forceinline__ float bitsf(unsigned u) { return __uint_as_float(u); }
__device__ __forceinline__ float lanebcf(float v, int l) {
    return __int_as_float(__builtin_amdgcn_readlane(__float_as_int(v), l));
}
__device__ __forceinline__ float f4c(const float4& a, int c) {
    switch (c & 3) { case 0: return a.x; case 1: return a.y; case 2: return a.z; default: return a.w; }
}

// ---- k_init: zero cnt8 + pack stacked weights [WZ | W1+WQ | W1] into MFMA B-frags ----
// WZ = Mt@W1 (bias 0), WPQ = W1 + Mb@W1 (bias b1 + bM0@W1), P-tile = W1 (bias b1).
__global__ void k_init(const float* __restrict__ M0, const float* __restrict__ W1,
                       const float* __restrict__ bM0, const float* __restrict__ b1,
                       int* __restrict__ cnt8, int M4,
                       ushort* __restrict__ WPhi, ushort* __restrict__ WPlo,
                       float* __restrict__ bias192) {
    int tid = blockIdx.x * 256 + threadIdx.x;
    int stride = gridDim.x * 256;
    int4 z4 = {0, 0, 0, 0};
    for (int i = tid; i < M4; i += stride) reinterpret_cast<int4*>(cnt8)[i] = z4;

    if (tid < 64 * 192) {
        int cc = tid % 192;
        int k  = tid / 192;
        float w;
        if (cc < 64) {
            float a = 0.f;
#pragma unroll
            for (int m = 0; m < HID; ++m) a = fmaf(M0[k * HID + m], W1[m * HID + cc], a);
            w = a;
        } else if (cc < 128) {
            int c = cc - 64;
            float a = W1[k * HID + c];
#pragma unroll
            for (int m = 0; m < HID; ++m) a = fmaf(M0[(HID + k) * HID + m], W1[m * HID + c], a);
            w = a;
        } else {
            w = W1[k * HID + (cc - 128)];
        }
        unsigned wb = __float_as_uint(w);
        ushort hi = (ushort)(wb >> 16);
        float hif = __uint_as_float(wb & 0xffff0000u);
        ushort lo = (ushort)(__float_as_uint(w - hif) >> 16);
        int ct = cc >> 4, s = k >> 5, l = ((k >> 3) & 3) * 16 + (cc & 15), j = k & 7;
        int fi = ((ct * 2 + s) * 64 + l) * 8 + j;
        WPhi[fi] = hi;
        WPlo[fi] = lo;
        if (k == 0) {
            float bv;
            if (cc < 64) bv = 0.f;
            else if (cc < 128) {
                int c = cc - 64;
                float a = b1[c];
#pragma unroll
                for (int m = 0; m < HID; ++m) a = fmaf(bM0[m], W1[m * HID + c], a);
                bv = a;
            } else bv = b1[cc - 128];
            bias192[cc] = bv;
        }
    }
}

// ---- fused: in-block hist (rank capture, fire-and-forget) + MFMA precompute ----
__global__ __launch_bounds__(256) void k_pre(
    const float* __restrict__ x, const float* __restrict__ W0, const float* __restrict__ b0,
    const ushort* __restrict__ WPhi, const ushort* __restrict__ WPlo,
    const float* __restrict__ bias192,
    ushort* __restrict__ zb, float* __restrict__ PQ, float* __restrict__ Pp, int N,
    const int* __restrict__ ei, int* __restrict__ cnt8, int* __restrict__ rank, int E)
{
    __shared__ ushort hhi[64 * 64];
    __shared__ ushort hlo[64 * 64];

    // --- hist slice: issue early; atomics drain under the compute below ---
    {
        int xcd = blockIdx.x & 7;
        int idx = blockIdx.x >> 3;
        int minBX = gridDim.x >> 3;                 // floor; trailing blocks just find s0>=s1
        int CH = (E + 7) / 8;
        int e0 = xcd * CH;
        int e1 = min(e0 + CH, E);
        int SC = (CH + minBX - 1) / minBX;
        int s0 = e0 + idx * SC;
        int s1 = min(s0 + SC, e1);
        int* cx = cnt8 + (size_t)xcd * N;
        for (int e = s0 + (int)threadIdx.x; e < s1; e += 256) {
            int dst = ei[E + e];
            rank[e] = atomicAdd(&cx[dst], 1);
        }
    }

    int tid  = threadIdx.x;
    int lane = tid & 63;
    int w    = tid >> 6;
    int n0   = blockIdx.x * 64;

    float w0c[IN_C];
#pragma unroll
    for (int k = 0; k < IN_C; ++k) w0c[k] = W0[k * HID + lane];
    float b0l = b0[lane];

    short8 Bhi[3][2], Blo[3][2];
    float bias[3];
#pragma unroll
    for (int i = 0; i < 3; ++i) {
        int ct = w * 3 + i;
#pragma unroll
        for (int s = 0; s < 2; ++s) {
            int fi = ((ct * 2 + s) * 64 + lane) * 8;
            Bhi[i][s] = *reinterpret_cast<const short8*>(WPhi + fi);
            Blo[i][s] = *reinterpret_cast<const short8*>(WPlo + fi);
        }
        bias[i] = bias192[ct * 16 + (lane & 15)];
    }

    // --- phase 1: wave-parallel x load (1 float4/lane covers the wave's 16 nodes) ---
    int nx = n0 + w * 16 + (lane >> 2);
    float4 xq = make_float4(0.f, 0.f, 0.f, 0.f);
    if (nx < N) xq = *reinterpret_cast<const float4*>(x + (size_t)nx * IN_C + (lane & 3) * 4);

#pragma unroll
    for (int nn = 0; nn < 16; ++nn) {
        float acc = b0l;
#pragma unroll
        for (int k = 0; k < IN_C; ++k)
            acc = fmaf(lanebcf(f4c(xq, k & 3), 4 * nn + (k >> 2)), w0c[k], acc);
        float h = fmaxf(acc, 0.f);
        unsigned hb = __float_as_uint(h);
        ushort hi = (ushort)(hb >> 16);
        float hif = __uint_as_float(hb & 0xffff0000u);
        ushort lo = (ushort)(__float_as_uint(h - hif) >> 16);
        int nl = w * 16 + nn;
        int u  = ((lane >> 3) ^ (nl & 7));
        int off = nl * 64 + u * 8 + (lane & 7);
        hhi[off] = hi;
        hlo[off] = lo;
    }
    __syncthreads();

    // --- phase 2: MFMA ---
#pragma unroll
    for (int st = 0; st < 4; ++st) {
        int nloc = st * 16 + (lane & 15);
        short8 Ahi[2], Alo[2];
#pragma unroll
        for (int s = 0; s < 2; ++s) {
            int u = (s * 4 + (lane >> 4)) ^ (nloc & 7);
            int off = nloc * 64 + u * 8;
            Ahi[s] = *reinterpret_cast<const short8*>(hhi + off);
            Alo[s] = *reinterpret_cast<const short8*>(hlo + off);
        }
#pragma unroll
        for (int i = 0; i < 3; ++i) {
            int ct = w * 3 + i;
            f32x4 acc = {bias[i], bias[i], bias[i], bias[i]};
#pragma unroll
            for (int s = 0; s < 2; ++s) {
                acc = __builtin_amdgcn_mfma_f32_16x16x32_bf16(Ahi[s], Bhi[i][s], acc, 0, 0, 0);
                acc = __builtin_amdgcn_mfma_f32_16x16x32_bf16(Ahi[s], Blo[i][s], acc, 0, 0, 0);
                acc = __builtin_amdgcn_mfma_f32_16x16x32_bf16(Alo[s], Bhi[i][s], acc, 0, 0, 0);
                acc = __builtin_amdgcn_mfma_f32_16x16x32_bf16(Alo[s], Blo[i][s], acc, 0, 0, 0);
            }
            int ch = ct * 16 + (lane & 15);
#pragma unroll
            for (int r = 0; r < 4; ++r) {
                int n = n0 + st * 16 + (lane >> 4) * 4 + r;
                if (n >= N) continue;
                float v = acc[r];
                if (ch < 64) {
                    unsigned u = __float_as_uint(v);
                    unsigned rr = (u + 0x7fffu + ((u >> 16) & 1u)) >> 16;
                    zb[(size_t)n * HID + ch] = (ushort)rr;
                } else if (ch < 128) {
                    PQ[(size_t)n * HID + (ch - 64)] = v;
                } else {
                    Pp[(size_t)n * HID + (ch - 128)] = v;
                }
            }
        }
    }
}

// ---- exclusive scan over M=8N elements, 16 per thread (4096/block) ----
__global__ void k_scan1(const int* __restrict__ cnt, int* __restrict__ rs,
                        int* __restrict__ bsum, int M) {
    __shared__ int lds[256];
    int t = threadIdx.x;
    int base = blockIdx.x * 4096 + t * 16;
    int v[16];
    if (base + 16 <= M) {
#pragma unroll
        for (int u = 0; u < 4; ++u) {
            int4 w = *reinterpret_cast<const int4*>(cnt + base + u * 4);
            v[u * 4 + 0] = w.x; v[u * 4 + 1] = w.y; v[u * 4 + 2] = w.z; v[u * 4 + 3] = w.w;
        }
    } else {
#pragma unroll
        for (int u = 0; u < 16; ++u) v[u] = (base + u < M) ? cnt[base + u] : 0;
    }
    int run = 0;
#pragma unroll
    for (int u = 0; u < 16; ++u) { int tv = v[u]; v[u] = run; run += tv; }
    lds[t] = run;
    __syncthreads();
#pragma unroll
    for (int off = 1; off < 256; off <<= 1) {
        int xw = (t >= off) ? lds[t - off] : 0;
        __syncthreads();
        lds[t] += xw;
        __syncthreads();
    }
    int excl = lds[t] - run;
    if (t == 255) bsum[blockIdx.x] = lds[255];
#pragma unroll
    for (int u = 0; u < 16; ++u)
        if (base + u < M) rs[base + u] = excl + v[u];
}

// rs[i] += exscan(bsum)[i>>12]; rs[M]=E
__global__ void k_scan_add(int* __restrict__ rs, const int* __restrict__ bsum,
                           int NB, int M, int E) {
    __shared__ int lds[256];
    __shared__ int excl[256];
    int t = threadIdx.x;
    int v = (t < NB) ? bsum[t] : 0;
    lds[t] = v;
    __syncthreads();
#pragma unroll
    for (int off = 1; off < 256; off <<= 1) {
        int xw = (t >= off) ? lds[t - off] : 0;
        __syncthreads();
        lds[t] += xw;
        __syncthreads();
    }
    excl[t] = lds[t] - v;
    __syncthreads();
    int i = blockIdx.x * 256 + t;
    if (i < M) rs[i] += excl[i >> 12];
    if (i == 0) rs[M] = E;
}

// ---- atomic-free scatter: csr8[rs[dst] + rank[e]] = src (XCD-local) ----
__global__ void k_scatter_r(const int* __restrict__ ei, const int* __restrict__ rank,
                            const int* __restrict__ rs8f, int* __restrict__ csr8,
                            int E, int N) {
    int xcd = blockIdx.x & 7;
    int o   = blockIdx.x >> 3;
    int Sx  = gridDim.x >> 3;
    int CH  = (E + 7) / 8;
    int e0  = xcd * CH;
    int e1  = min(e0 + CH, E);
    const int* rx = rs8f + (size_t)xcd * N;
    for (int e = e0 + o * 256 + (int)threadIdx.x; e < e1; e += Sx * 256) {
        int srcn = ei[e];
        int dstn = ei[E + e];
        csr8[rx[dstn] + rank[e]] = srcn;
    }
}

// ---- bf16 gather (2 edges/round per 16-lane group) + elementwise epilogue ----
__global__ __launch_bounds__(256) void k_final(
    const ushort* __restrict__ zb, const float* __restrict__ PQ, const float* __restrict__ Pp,
    const int* __restrict__ rs8f, const int* __restrict__ csr8,
    const float* __restrict__ W2, const float* __restrict__ b2,
    float* __restrict__ out, int N)
{
    int lane = threadIdx.x & 63;
    int g    = lane >> 4;
    int ql   = lane & 15;
    int oct  = ql & 7;
    int half = ql >> 3;
    int wid  = (blockIdx.x * 256 + threadIdx.x) >> 6;
    int nw   = (gridDim.x * 256) >> 6;

    int c0 = oct * 8 + half * 4;
    float4 w2v = *reinterpret_cast<const float4*>(W2 + c0);
    float b2s = b2[0];

    for (int n0 = wid * 4; n0 < N; n0 += nw * 4) {
        int ng   = n0 + g;
        bool okg = ng < N;

        int rv = okg ? rs8f[(size_t)oct * N + ng + half] : 0;
        int bx[8], cum[8];
        int dsum = 0;
#pragma unroll
        for (int xx = 0; xx < 8; ++xx) {
            int bb = __shfl(rv, g * 16 + xx);
            int ee = __shfl(rv, g * 16 + 8 + xx);
            bx[xx] = bb;
            cum[xx] = dsum;
            dsum += (ee - bb);
        }
        int deg = dsum;
        int md = deg;
        md = max(md, __shfl_xor(md, 16));
        md = max(md, __shfl_xor(md, 32));

        float acc[8];
#pragma unroll
        for (int i = 0; i < 8; ++i) acc[i] = 0.f;

        for (int c = 0; c < md; c += 32) {
            int j0 = c + ql, j1 = c + 16 + ql;
            int a0 = bx[0] + j0, a1 = bx[0] + j1;
#pragma unroll
            for (int xx = 1; xx < 8; ++xx) {
                a0 = (j0 >= cum[xx]) ? (bx[xx] + (j0 - cum[xx])) : a0;
                a1 = (j1 >= cum[xx]) ? (bx[xx] + (j1 - cum[xx])) : a1;
            }
            int ia = (j0 < deg) ? csr8[a0] : -1;
            int ib = (j1 < deg) ? csr8[a1] : -1;
#pragma unroll
            for (int tb = 0; tb < 4; ++tb) {
                if (tb > 0 && md <= c + 8 * tb) break;
                int srcs[4];
#pragma unroll
                for (int t4 = 0; t4 < 4; ++t4) {
                    int t = tb * 4 + t4;
                    int e = 2 * t + half;
                    srcs[t4] = __shfl(tb < 2 ? ia : ib, g * 16 + (e & 15));
                }
                uint4 rw[4];
#pragma unroll
                for (int t4 = 0; t4 < 4; ++t4) {
                    int s = srcs[t4] < 0 ? 0 : srcs[t4];
                    rw[t4] = *reinterpret_cast<const uint4*>(zb + (size_t)s * HID + oct * 8);
                }
#pragma unroll
                for (int t4 = 0; t4 < 4; ++t4) {
                    if (srcs[t4] >= 0) {
                        uint4 wv = rw[t4];
                        acc[0] += bitsf(wv.x << 16); acc[1] += bitsf(wv.x & 0xffff0000u);
                        acc[2] += bitsf(wv.y << 16); acc[3] += bitsf(wv.y & 0xffff0000u);
                        acc[4] += bitsf(wv.z << 16); acc[5] += bitsf(wv.z & 0xffff0000u);
                        acc[6] += bitsf(wv.w << 16); acc[7] += bitsf(wv.w & 0xffff0000u);
                    }
                }
            }
        }
#pragma unroll
        for (int i = 0; i < 8; ++i) acc[i] += __shfl_xor(acc[i], 8);

        float s0 = half ? acc[4] : acc[0];
        float s1 = half ? acc[5] : acc[1];
        float s2 = half ? acc[6] : acc[2];
        float s3 = half ? acc[7] : acc[3];

        float4 base = make_float4(0.f, 0.f, 0.f, 0.f);
        if (okg) {
            base = *reinterpret_cast<const float4*>(PQ + (size_t)ng * HID + c0);
            if (deg == 0)
                base = *reinterpret_cast<const float4*>(Pp + (size_t)ng * HID + c0);
        }
        float rcpd = (deg > 0) ? (1.f / (float)deg) : 0.f;
        float y0 = base.x + s0 * rcpd;
        float y1 = base.y + s1 * rcpd;
        float y2 = base.z + s2 * rcpd;
        float y3 = base.w + s3 * rcpd;

        float part = fmaxf(y0, 0.f) * w2v.x + fmaxf(y1, 0.f) * w2v.y +
                     fmaxf(y2, 0.f) * w2v.z + fmaxf(y3, 0.f) * w2v.w;
#pragma unroll
        for (int off = 1; off < 16; off <<= 1) part += __shfl_xor(part, off);
        if (ql == 0 && okg) out[ng] = part + b2s;
    }
}

extern "C" void kernel_launch(void* const* d_in, const int* in_sizes, int n_in,
                              void* d_out, int out_size, void* d_ws, size_t ws_size,
                              hipStream_t stream) {
    const float* x   = (const float*)d_in[0];
    const int*   ei  = (const int*)d_in[1];
    const float* W0  = (const float*)d_in[2];
    const float* b0  = (const float*)d_in[3];
    const float* W1  = (const float*)d_in[4];
    const float* b1  = (const float*)d_in[5];
    const float* W2  = (const float*)d_in[6];
    const float* b2  = (const float*)d_in[7];
    const float* M0  = (const float*)d_in[8];
    const float* bM0 = (const float*)d_in[9];

    int N = in_sizes[0] / IN_C;
    int E = in_sizes[1] / 2;
    int M = 8 * N;
    int NB = (M + 4095) / 4096;   // <= 256 for N <= 131072

    ushort* zb     = (ushort*)d_ws;                   // N*64 bf16
    float*  PQ     = (float*)(zb + (size_t)N * HID);  // N*64
    float*  Pp     = PQ + (size_t)N * HID;            // N*64
    ushort* WPhi   = (ushort*)(Pp + (size_t)N * HID); // 12288
    ushort* WPlo   = WPhi + 12288;                    // 12288
    float*  bias192= (float*)(WPlo + 12288);          // 192
    int*    cnt8   = (int*)(bias192 + 192);           // 8N
    int*    rs8f   = cnt8 + (size_t)M;                // 8N+1
    int*    bsum   = rs8f + (size_t)M + 1;            // 256
    int*    rank   = bsum + 256;                      // E
    int*    csr8   = rank + (size_t)E;                // E
    float*  out    = (float*)d_out;

    int npre = (N + 63) / 64;

    k_init<<<128, 256, 0, stream>>>(M0, W1, bM0, b1, cnt8, M / 4, WPhi, WPlo, bias192);
    // scan of cnt8 must see completed hist: k_pre ends -> kernel boundary sync
    k_pre<<<npre, 256, 0, stream>>>(x, W0, b0, WPhi, WPlo, bias192,
                                    zb, PQ, Pp, N, ei, cnt8, rank, E);
    k_scan1<<<NB, 256, 0, stream>>>(cnt8, rs8f, bsum, M);
    k_scan_add<<<(M + 255) / 256, 256, 0, stream>>>(rs8f, bsum, NB, M, E);
    k_scatter_r<<<1600, 256, 0, stream>>>(ei, rank, rs8f, csr8, E, N);
    k_final<<<2048, 256, 0, stream>>>(zb, PQ, Pp, rs8f, csr8, W2, b2, out, N);
}